// Round 4
// baseline (1595.975 us; speedup 1.0000x reference)
//
#include <hip/hip_runtime.h>
#include <hip/hip_fp16.h>
#include <cmath>

#define N_NODES 100000
#define N_EDGES 3200000
#define ALPHA   0.1f
#define ITERS   10
#define NBUK    1024
#define RPB     98      // rows per bucket; NBUK*RPB = 100352 >= N_NODES

typedef __attribute__((ext_vector_type(8))) short short8;
typedef __attribute__((ext_vector_type(4))) short short4v;
typedef __attribute__((ext_vector_type(4))) float f32x4;

__device__ __forceinline__ short f2bf(float x) {
    union { float f; unsigned u; } v; v.f = x;
    unsigned r = v.u + 0x7fffu + ((v.u >> 16) & 1u);   // RNE
    return (short)(r >> 16);
}

// ---------------------------------------------------------------------------
// One-time weight prep: W1[512][64] -> W1t[64][512] bf16 ; W2[64][64] -> W2t[64][64] bf16
// ---------------------------------------------------------------------------
__global__ void prep_w(const float* __restrict__ W1, const float* __restrict__ W2,
                       short* __restrict__ W1t, short* __restrict__ W2t)
{
    int t = blockIdx.x * 256 + threadIdx.x;
    if (t < 512 * 64) { int k = t >> 6, c = t & 63; W1t[c * 512 + k] = f2bf(W1[t]); }
    if (t < 64 * 64)  { int k = t >> 6, c = t & 63; W2t[c * 64 + k]  = f2bf(W2[t]); }
}

// ---------------------------------------------------------------------------
// Fused MFMA MLP: z = relu(F @ W1 + b1) @ W2 + b2   (also writes q0 = fp16(z))
// ---------------------------------------------------------------------------
__global__ __launch_bounds__(256) void mlp_mfma(
    const float* __restrict__ F, const short* __restrict__ W1t,
    const short* __restrict__ W2t, const float* __restrict__ b1,
    const float* __restrict__ b2, float* __restrict__ z, __half* __restrict__ q0)
{
    __shared__ short Ft[64 * 128];   // 16KB feature tile (bf16, swizzled)
    __shared__ short Wt[64 * 128];   // 16KB W1t tile [col][k]
    __shared__ short Ht[64 * 64];    // 8KB hidden (bf16, swizzled)
    __shared__ short W2s[64 * 64];   // 8KB W2t [col][k]

    const int t  = threadIdx.x;
    const int l  = t & 63;
    const int wv = t >> 6;          // wave 0..3
    const int wr = wv * 16;         // wave's row base within tile
    const long base = (long)blockIdx.x * 64;

    f32x4 acc[4] = {};
    for (int kt = 0; kt < 4; ++kt) {
#pragma unroll
        for (int j = 0; j < 8; ++j) {
            int idx4 = (t + 256 * j) * 4;
            int row = idx4 >> 7, k = idx4 & 127;
            long grow = base + row; if (grow > N_NODES - 1) grow = N_NODES - 1;
            float4 v = *(const float4*)(F + grow * 512 + kt * 128 + k);
            short4v s = { f2bf(v.x), f2bf(v.y), f2bf(v.z), f2bf(v.w) };
            *(short4v*)&Ft[(row * 128 + k) ^ ((row & 7) << 3)] = s;
        }
#pragma unroll
        for (int j = 0; j < 8; ++j) {
            int h4 = (t + 256 * j) * 4;
            int row = h4 >> 7, k = h4 & 127;
            uint2 v = *(const uint2*)(W1t + row * 512 + kt * 128 + k);
            *(uint2*)&Wt[(row * 128 + k) ^ ((row & 7) << 3)] = v;
        }
        if (kt == 0) {
#pragma unroll
            for (int j = 0; j < 4; ++j) {
                int h4 = (t + 256 * j) * 4;
                int row = h4 >> 6, k = h4 & 63;
                uint2 v = *(const uint2*)(W2t + row * 64 + k);
                *(uint2*)&W2s[(row * 64 + k) ^ ((row & 7) << 3)] = v;
            }
        }
        __syncthreads();
#pragma unroll
        for (int kc = 0; kc < 4; ++kc) {
            int kb = kc * 32 + (l >> 4) * 8;
            int ar = wr + (l & 15);
            short8 a = *(const short8*)&Ft[(ar * 128 + kb) ^ ((ar & 7) << 3)];
#pragma unroll
            for (int n = 0; n < 4; ++n) {
                int bc = n * 16 + (l & 15);
                short8 b = *(const short8*)&Wt[(bc * 128 + kb) ^ ((bc & 7) << 3)];
                acc[n] = __builtin_amdgcn_mfma_f32_16x16x32_bf16(a, b, acc[n], 0, 0, 0);
            }
        }
        __syncthreads();
    }

#pragma unroll
    for (int n = 0; n < 4; ++n) {
        int col = n * 16 + (l & 15);
        float bv = b1[col];
#pragma unroll
        for (int i = 0; i < 4; ++i) {
            int row = wr + (l >> 4) * 4 + i;
            float hv = fmaxf(acc[n][i] + bv, 0.0f);
            Ht[(row * 64 + col) ^ ((row & 7) << 3)] = f2bf(hv);
        }
    }
    f32x4 acc2[4] = {};
#pragma unroll
    for (int kc = 0; kc < 2; ++kc) {
        int kb = kc * 32 + (l >> 4) * 8;
        int ar = wr + (l & 15);
        short8 a = *(const short8*)&Ht[(ar * 64 + kb) ^ ((ar & 7) << 3)];
#pragma unroll
        for (int n = 0; n < 4; ++n) {
            int bc = n * 16 + (l & 15);
            short8 b = *(const short8*)&W2s[(bc * 64 + kb) ^ ((bc & 7) << 3)];
            acc2[n] = __builtin_amdgcn_mfma_f32_16x16x32_bf16(a, b, acc2[n], 0, 0, 0);
        }
    }
#pragma unroll
    for (int n = 0; n < 4; ++n) {
        int col = n * 16 + (l & 15);
        float bv = b2[col];
#pragma unroll
        for (int i = 0; i < 4; ++i) {
            long row = base + wr + (l >> 4) * 4 + i;
            if (row < N_NODES) {
                float zv = acc2[n][i] + bv;
                z[row * 64 + col]  = zv;
                q0[row * 64 + col] = __float2half(zv);
            }
        }
    }
}

// ---------------------------------------------------------------------------
// CSR build: hist -> scan -> bucketed two-phase scatter
// ---------------------------------------------------------------------------
__global__ void hist_kernel(const int* __restrict__ rows, int* __restrict__ deg, int E)
{
    int i = blockIdx.x * blockDim.x + threadIdx.x;
    if (i < E) atomicAdd(&deg[rows[i]], 1);
}

__global__ void block_sum_kernel(const int* __restrict__ deg, int* __restrict__ bsum, int N)
{
    __shared__ int s[256];
    int g = blockIdx.x * 256 + threadIdx.x;
    s[threadIdx.x] = (g < N) ? deg[g] : 0;
    __syncthreads();
    for (int off = 128; off > 0; off >>= 1) {
        if (threadIdx.x < off) s[threadIdx.x] += s[threadIdx.x + off];
        __syncthreads();
    }
    if (threadIdx.x == 0) bsum[blockIdx.x] = s[0];
}

__global__ void scan_bsum_kernel(const int* __restrict__ bsum, int* __restrict__ boff, int nb)
{
    __shared__ int s[512];
    int t = threadIdx.x;
    int v = (t < nb) ? bsum[t] : 0;
    s[t] = v;
    __syncthreads();
    for (int off = 1; off < 512; off <<= 1) {
        int x = (t >= off) ? s[t - off] : 0;
        __syncthreads();
        s[t] += x;
        __syncthreads();
    }
    if (t < nb) boff[t] = s[t] - v;   // exclusive
}

__global__ void scan_chunks_kernel(const int* __restrict__ deg, const int* __restrict__ boff,
                                   int* __restrict__ row_ptr, int N)
{
    __shared__ int s[256];
    int tid = threadIdx.x;
    int g = blockIdx.x * 256 + tid;
    int v = (g < N) ? deg[g] : 0;
    s[tid] = v;
    __syncthreads();
    for (int off = 1; off < 256; off <<= 1) {
        int x = (tid >= off) ? s[tid - off] : 0;
        __syncthreads();
        s[tid] += x;
        __syncthreads();
    }
    int incl = s[tid];
    if (g < N) row_ptr[g] = boff[blockIdx.x] + incl - v;
    if (g == N - 1) row_ptr[N] = boff[blockIdx.x] + incl;
}

// bucket cursors = rowp at each bucket's first row
__global__ void init_bcur(const int* __restrict__ rowp, int* __restrict__ bcur)
{
    int b = blockIdx.x * 256 + threadIdx.x;
    if (b < NBUK) {
        int r = b * RPB; if (r > N_NODES) r = N_NODES;
        bcur[b] = rowp[r];
    }
}

// pass 1: scatter edges into bucket-contiguous staging (sequential within bucket
// -> full-line fills, no write amplification). rec = {col|rowoff<<17, w bits}
__global__ void bucket_scatter(const int* __restrict__ rows, const int* __restrict__ cols,
                               const float* __restrict__ w, int* __restrict__ bcur,
                               uint2* __restrict__ stg, int E)
{
    int i = blockIdx.x * blockDim.x + threadIdx.x;
    if (i < E) {
        int r = rows[i];
        int b = r / RPB;
        int pos = atomicAdd(&bcur[b], 1);
        float ws = w[i] * ((1.0f - ALPHA) / 16.0f);
        unsigned meta = (unsigned)cols[i] | ((unsigned)(r - b * RPB) << 17);
        stg[pos] = make_uint2(meta, __float_as_uint(ws));
    }
}

// pass 2: one block per bucket; LDS row cursors; write final cw into the
// bucket's contiguous ~25KB window (L2-local, full-line fills).
__global__ __launch_bounds__(256) void bucket_sort(const int* __restrict__ rowp,
                                                   const uint2* __restrict__ stg,
                                                   unsigned long long* __restrict__ cw)
{
    __shared__ int lcur[RPB];
    int b = blockIdx.x;
    int rowlo = b * RPB;
    if (rowlo >= N_NODES) return;
    int rowhi = rowlo + RPB; if (rowhi > N_NODES) rowhi = N_NODES;
    int nrows = rowhi - rowlo;
    for (int r = threadIdx.x; r < nrows; r += 256) lcur[r] = rowp[rowlo + r];
    __syncthreads();
    int base = rowp[rowlo];
    int cnt  = rowp[rowhi] - base;
    for (int j = threadIdx.x; j < cnt; j += 256) {
        uint2 rec = stg[base + j];
        int roff = rec.x >> 17;
        unsigned col = rec.x & 0x1FFFFu;
        int pos = atomicAdd(&lcur[roff], 1);
        cw[pos] = (unsigned long long)col | ((unsigned long long)rec.y << 32);
    }
}

// ---------------------------------------------------------------------------
// SpMM on scaled fp16 state: q_t = sum w' * q_{t-1}[col] + beta_t * z
// One wave per row; 16 lanes x 4 labels, 8 edges in flight (unroll 2).
// ---------------------------------------------------------------------------
template <int LAST>
__global__ __launch_bounds__(256) void spmm_kernel(
    const int* __restrict__ rowp, const unsigned long long* __restrict__ cw,
    const __half* __restrict__ qin, const float* __restrict__ z,
    float beta, float outscale,
    __half* __restrict__ qout, float* __restrict__ out)
{
    const int wid = blockIdx.x * 4 + (threadIdx.x >> 6);
    if (wid >= N_NODES) return;
    const int lane = threadIdx.x & 63;
    const int sub  = lane >> 4;
    const int l16  = lane & 15;

    const int start = rowp[wid];
    const int end   = rowp[wid + 1];

    float ax = 0.f, ay = 0.f, az = 0.f, aw = 0.f;
    int e = start + sub;
    for (; e + 4 < end; e += 8) {
        unsigned long long pc0 = cw[e];
        unsigned long long pc1 = cw[e + 4];
        int   c0  = (int)(unsigned)pc0;
        int   c1  = (int)(unsigned)pc1;
        float w0 = __uint_as_float((unsigned)(pc0 >> 32));
        float w1 = __uint_as_float((unsigned)(pc1 >> 32));
        uint2 v0 = *(const uint2*)(qin + (long)c0 * 64 + l16 * 4);
        uint2 v1 = *(const uint2*)(qin + (long)c1 * 64 + l16 * 4);
        __half2 a0 = *reinterpret_cast<__half2*>(&v0.x);
        __half2 a1 = *reinterpret_cast<__half2*>(&v0.y);
        __half2 b0 = *reinterpret_cast<__half2*>(&v1.x);
        __half2 b1 = *reinterpret_cast<__half2*>(&v1.y);
        float2 f0 = __half22float2(a0), f1 = __half22float2(a1);
        float2 g0 = __half22float2(b0), g1 = __half22float2(b1);
        ax += w0 * f0.x + w1 * g0.x;
        ay += w0 * f0.y + w1 * g0.y;
        az += w0 * f1.x + w1 * g1.x;
        aw += w0 * f1.y + w1 * g1.y;
    }
    if (e < end) {
        unsigned long long pc = cw[e];
        int   c  = (int)(unsigned)pc;
        float ww = __uint_as_float((unsigned)(pc >> 32));
        uint2 v = *(const uint2*)(qin + (long)c * 64 + l16 * 4);
        __half2 h0 = *reinterpret_cast<__half2*>(&v.x);
        __half2 h1 = *reinterpret_cast<__half2*>(&v.y);
        float2 f0 = __half22float2(h0);
        float2 f1 = __half22float2(h1);
        ax += ww * f0.x; ay += ww * f0.y; az += ww * f1.x; aw += ww * f1.y;
    }
    ax += __shfl_xor(ax, 16); ay += __shfl_xor(ay, 16);
    az += __shfl_xor(az, 16); aw += __shfl_xor(aw, 16);
    ax += __shfl_xor(ax, 32); ay += __shfl_xor(ay, 32);
    az += __shfl_xor(az, 32); aw += __shfl_xor(aw, 32);

    if (sub == 0) {
        float4 zv = *(const float4*)(z + (long)wid * 64 + l16 * 4);
        float ox = ax + beta * zv.x;
        float oy = ay + beta * zv.y;
        float oz = az + beta * zv.z;
        float ow = aw + beta * zv.w;
        if (LAST) {
            float4 o = { outscale * ox, outscale * oy, outscale * oz, outscale * ow };
            *(float4*)(out + (long)wid * 64 + l16 * 4) = o;
        } else {
            __half2 p0 = __floats2half2_rn(ox, oy);
            __half2 p1 = __floats2half2_rn(oz, ow);
            uint2 pv = { *(unsigned*)&p0, *(unsigned*)&p1 };
            *(uint2*)(qout + (long)wid * 64 + l16 * 4) = pv;
        }
    }
}

// ---------------------------------------------------------------------------
extern "C" void kernel_launch(void* const* d_in, const int* in_sizes, int n_in,
                              void* d_out, int out_size, void* d_ws, size_t ws_size,
                              hipStream_t stream)
{
    const float* features = (const float*)d_in[0];
    const float* W1 = (const float*)d_in[1];
    const float* b1 = (const float*)d_in[2];
    const float* W2 = (const float*)d_in[3];
    const float* b2 = (const float*)d_in[4];
    const float* ew = (const float*)d_in[5];
    const int*   ei = (const int*)d_in[6];
    const int* erow = ei;
    const int* ecol = ei + N_EDGES;
    float* out = (float*)d_out;

    char* ws = (char*)d_ws;
    size_t off = 0;
    auto alloc = [&](size_t bytes) {
        size_t c = off;
        off += (bytes + 255) & ~(size_t)255;
        return c;
    };
    float* z      = (float*)(ws + alloc((size_t)N_NODES * 64 * 4));
    __half* q0    = (__half*)(ws + alloc((size_t)N_NODES * 64 * 2));
    __half* qA    = (__half*)(ws + alloc((size_t)N_NODES * 64 * 2));
    unsigned long long* cw = (unsigned long long*)(ws + alloc((size_t)N_EDGES * 8));
    uint2* stg    = (uint2*)(ws + alloc((size_t)N_EDGES * 8));
    short* W1t    = (short*)(ws + alloc((size_t)512 * 64 * 2));
    short* W2t    = (short*)(ws + alloc((size_t)64 * 64 * 2));
    int*   deg    = (int*)  (ws + alloc((size_t)N_NODES * 4));
    int*   rowp   = (int*)  (ws + alloc((size_t)(N_NODES + 1) * 4));
    int*   bcur   = (int*)  (ws + alloc((size_t)NBUK * 4));
    int*   bsum   = (int*)  (ws + alloc((size_t)512 * 4));
    int*   boff   = (int*)  (ws + alloc((size_t)512 * 4));
    (void)ws_size; (void)in_sizes; (void)n_in; (void)out_size;

    // 1) weight prep + MLP head (writes z fp32 and q0 fp16)
    prep_w<<<128, 256, 0, stream>>>(W1, W2, W1t, W2t);
    mlp_mfma<<<(N_NODES + 63) / 64, 256, 0, stream>>>(features, W1t, W2t, b1, b2, z, q0);

    // 2) CSR build keyed by destination row (bucketed two-phase scatter)
    hipMemsetAsync(deg, 0, (size_t)N_NODES * 4, stream);
    hist_kernel<<<(N_EDGES + 255) / 256, 256, 0, stream>>>(erow, deg, N_EDGES);
    const int nb = (N_NODES + 255) / 256;  // 391
    block_sum_kernel<<<nb, 256, 0, stream>>>(deg, bsum, N_NODES);
    scan_bsum_kernel<<<1, 512, 0, stream>>>(bsum, boff, nb);
    scan_chunks_kernel<<<nb, 256, 0, stream>>>(deg, boff, rowp, N_NODES);
    init_bcur<<<(NBUK + 255) / 256, 256, 0, stream>>>(rowp, bcur);
    bucket_scatter<<<(N_EDGES + 255) / 256, 256, 0, stream>>>(erow, ecol, ew, bcur, stg, N_EDGES);
    bucket_sort<<<NBUK, 256, 0, stream>>>(rowp, stg, cw);

    // 3) 10 propagation iterations on scaled fp16 state (c = 16)
    const __half* qi = q0;
    for (int it = 1; it < ITERS; ++it) {
        __half* qo = (it & 1) ? qA : q0;
        float beta = (float)(0.1 / pow(16.0, (double)it));
        spmm_kernel<0><<<(N_NODES + 3) / 4, 256, 0, stream>>>(rowp, cw, qi, z, beta, 1.0f, qo, nullptr);
        qi = qo;
    }
    float beta10 = (float)(0.1 / pow(16.0, 10.0));
    float osc    = (float)pow(16.0, 10.0);
    spmm_kernel<1><<<(N_NODES + 3) / 4, 256, 0, stream>>>(rowp, cw, qi, z, beta10, osc, nullptr, out);
}

// Round 5
// 1053.393 us; speedup vs baseline: 1.5151x; 1.5151x over previous
//
#include <hip/hip_runtime.h>
#include <hip/hip_fp16.h>
#include <cmath>

#define N_NODES 100000
#define N_EDGES 3200000
#define ALPHA   0.1f
#define ITERS   10
#define NBUK    1024
#define RPB     98      // rows per bucket; NBUK*RPB = 100352 >= N_NODES
#define CHUNK   8192
#define NCH     391     // ceil(N_EDGES / CHUNK)

typedef __attribute__((ext_vector_type(8))) short short8;
typedef __attribute__((ext_vector_type(4))) short short4v;
typedef __attribute__((ext_vector_type(4))) float f32x4;

__device__ __forceinline__ short f2bf(float x) {
    union { float f; unsigned u; } v; v.f = x;
    unsigned r = v.u + 0x7fffu + ((v.u >> 16) & 1u);   // RNE
    return (short)(r >> 16);
}

// ---------------------------------------------------------------------------
// One-time weight prep: W1[512][64] -> W1t[64][512] bf16 ; W2 -> W2t bf16
// ---------------------------------------------------------------------------
__global__ void prep_w(const float* __restrict__ W1, const float* __restrict__ W2,
                       short* __restrict__ W1t, short* __restrict__ W2t)
{
    int t = blockIdx.x * 256 + threadIdx.x;
    if (t < 512 * 64) { int k = t >> 6, c = t & 63; W1t[c * 512 + k] = f2bf(W1[t]); }
    if (t < 64 * 64)  { int k = t >> 6, c = t & 63; W2t[c * 64 + k]  = f2bf(W2[t]); }
}

// ---------------------------------------------------------------------------
// Fused MFMA MLP: z = relu(F @ W1 + b1) @ W2 + b2   (also writes q0 = fp16(z))
// ---------------------------------------------------------------------------
__global__ __launch_bounds__(256) void mlp_mfma(
    const float* __restrict__ F, const short* __restrict__ W1t,
    const short* __restrict__ W2t, const float* __restrict__ b1,
    const float* __restrict__ b2, float* __restrict__ z, __half* __restrict__ q0)
{
    __shared__ short Ft[64 * 128];
    __shared__ short Wt[64 * 128];
    __shared__ short Ht[64 * 64];
    __shared__ short W2s[64 * 64];

    const int t  = threadIdx.x;
    const int l  = t & 63;
    const int wv = t >> 6;
    const int wr = wv * 16;
    const long base = (long)blockIdx.x * 64;

    f32x4 acc[4] = {};
    for (int kt = 0; kt < 4; ++kt) {
#pragma unroll
        for (int j = 0; j < 8; ++j) {
            int idx4 = (t + 256 * j) * 4;
            int row = idx4 >> 7, k = idx4 & 127;
            long grow = base + row; if (grow > N_NODES - 1) grow = N_NODES - 1;
            float4 v = *(const float4*)(F + grow * 512 + kt * 128 + k);
            short4v s = { f2bf(v.x), f2bf(v.y), f2bf(v.z), f2bf(v.w) };
            *(short4v*)&Ft[(row * 128 + k) ^ ((row & 7) << 3)] = s;
        }
#pragma unroll
        for (int j = 0; j < 8; ++j) {
            int h4 = (t + 256 * j) * 4;
            int row = h4 >> 7, k = h4 & 127;
            uint2 v = *(const uint2*)(W1t + row * 512 + kt * 128 + k);
            *(uint2*)&Wt[(row * 128 + k) ^ ((row & 7) << 3)] = v;
        }
        if (kt == 0) {
#pragma unroll
            for (int j = 0; j < 4; ++j) {
                int h4 = (t + 256 * j) * 4;
                int row = h4 >> 6, k = h4 & 63;
                uint2 v = *(const uint2*)(W2t + row * 64 + k);
                *(uint2*)&W2s[(row * 64 + k) ^ ((row & 7) << 3)] = v;
            }
        }
        __syncthreads();
#pragma unroll
        for (int kc = 0; kc < 4; ++kc) {
            int kb = kc * 32 + (l >> 4) * 8;
            int ar = wr + (l & 15);
            short8 a = *(const short8*)&Ft[(ar * 128 + kb) ^ ((ar & 7) << 3)];
#pragma unroll
            for (int n = 0; n < 4; ++n) {
                int bc = n * 16 + (l & 15);
                short8 b = *(const short8*)&Wt[(bc * 128 + kb) ^ ((bc & 7) << 3)];
                acc[n] = __builtin_amdgcn_mfma_f32_16x16x32_bf16(a, b, acc[n], 0, 0, 0);
            }
        }
        __syncthreads();
    }

#pragma unroll
    for (int n = 0; n < 4; ++n) {
        int col = n * 16 + (l & 15);
        float bv = b1[col];
#pragma unroll
        for (int i = 0; i < 4; ++i) {
            int row = wr + (l >> 4) * 4 + i;
            float hv = fmaxf(acc[n][i] + bv, 0.0f);
            Ht[(row * 64 + col) ^ ((row & 7) << 3)] = f2bf(hv);
        }
    }
    f32x4 acc2[4] = {};
#pragma unroll
    for (int kc = 0; kc < 2; ++kc) {
        int kb = kc * 32 + (l >> 4) * 8;
        int ar = wr + (l & 15);
        short8 a = *(const short8*)&Ht[(ar * 64 + kb) ^ ((ar & 7) << 3)];
#pragma unroll
        for (int n = 0; n < 4; ++n) {
            int bc = n * 16 + (l & 15);
            short8 b = *(const short8*)&W2s[(bc * 64 + kb) ^ ((bc & 7) << 3)];
            acc2[n] = __builtin_amdgcn_mfma_f32_16x16x32_bf16(a, b, acc2[n], 0, 0, 0);
        }
    }
#pragma unroll
    for (int n = 0; n < 4; ++n) {
        int col = n * 16 + (l & 15);
        float bv = b2[col];
#pragma unroll
        for (int i = 0; i < 4; ++i) {
            long row = base + wr + (l >> 4) * 4 + i;
            if (row < N_NODES) {
                float zv = acc2[n][i] + bv;
                z[row * 64 + col]  = zv;
                q0[row * 64 + col] = __float2half(zv);
            }
        }
    }
}

// ---------------------------------------------------------------------------
// Row-degree CSR pointers (for pass-2 row sort + spmm)
// ---------------------------------------------------------------------------
__global__ void hist_kernel(const int* __restrict__ rows, int* __restrict__ deg, int E)
{
    int i = blockIdx.x * blockDim.x + threadIdx.x;
    if (i < E) atomicAdd(&deg[rows[i]], 1);
}

__global__ void block_sum_kernel(const int* __restrict__ deg, int* __restrict__ bsum, int N)
{
    __shared__ int s[256];
    int g = blockIdx.x * 256 + threadIdx.x;
    s[threadIdx.x] = (g < N) ? deg[g] : 0;
    __syncthreads();
    for (int off = 128; off > 0; off >>= 1) {
        if (threadIdx.x < off) s[threadIdx.x] += s[threadIdx.x + off];
        __syncthreads();
    }
    if (threadIdx.x == 0) bsum[blockIdx.x] = s[0];
}

__global__ void scan_bsum_kernel(const int* __restrict__ bsum, int* __restrict__ boff, int nb)
{
    __shared__ int s[512];
    int t = threadIdx.x;
    int v = (t < nb) ? bsum[t] : 0;
    s[t] = v;
    __syncthreads();
    for (int off = 1; off < 512; off <<= 1) {
        int x = (t >= off) ? s[t - off] : 0;
        __syncthreads();
        s[t] += x;
        __syncthreads();
    }
    if (t < nb) boff[t] = s[t] - v;   // exclusive
}

__global__ void scan_chunks_kernel(const int* __restrict__ deg, const int* __restrict__ boff,
                                   int* __restrict__ row_ptr, int N)
{
    __shared__ int s[256];
    int tid = threadIdx.x;
    int g = blockIdx.x * 256 + tid;
    int v = (g < N) ? deg[g] : 0;
    s[tid] = v;
    __syncthreads();
    for (int off = 1; off < 256; off <<= 1) {
        int x = (tid >= off) ? s[tid - off] : 0;
        __syncthreads();
        s[tid] += x;
        __syncthreads();
    }
    int incl = s[tid];
    if (g < N) row_ptr[g] = boff[blockIdx.x] + incl - v;
    if (g == N - 1) row_ptr[N] = boff[blockIdx.x] + incl;
}

// ---------------------------------------------------------------------------
// Radix-partition by bucket (counting sort, no global atomics):
// bhist -> bscan (per-bucket over chunks) -> scan_btot -> bpart
// ---------------------------------------------------------------------------
__global__ __launch_bounds__(256) void bhist(const int* __restrict__ rows, int* __restrict__ gh)
{
    __shared__ int cnt[NBUK];
    for (int i = threadIdx.x; i < NBUK; i += 256) cnt[i] = 0;
    __syncthreads();
    int base = blockIdx.x * CHUNK;
    int end  = base + CHUNK; if (end > N_EDGES) end = N_EDGES;
    for (int i = base + threadIdx.x; i < end; i += 256)
        atomicAdd(&cnt[rows[i] / RPB], 1);
    __syncthreads();
    for (int i = threadIdx.x; i < NBUK; i += 256)
        gh[i * NCH + blockIdx.x] = cnt[i];
}

// one block per bucket: exclusive scan of its NCH chunk counts (in place) + total
__global__ __launch_bounds__(512) void bscan(int* __restrict__ gh, int* __restrict__ btot)
{
    __shared__ int s[512];
    int k = blockIdx.x;
    int t = threadIdx.x;
    int v = (t < NCH) ? gh[k * NCH + t] : 0;
    s[t] = v;
    __syncthreads();
    for (int off = 1; off < 512; off <<= 1) {
        int x = (t >= off) ? s[t - off] : 0;
        __syncthreads();
        s[t] += x;
        __syncthreads();
    }
    if (t < NCH) gh[k * NCH + t] = s[t] - v;   // exclusive within bucket
    if (t == NCH - 1) btot[k] = s[t];
}

__global__ __launch_bounds__(1024) void scan_btot(const int* __restrict__ btot, int* __restrict__ bbase)
{
    __shared__ int s[1024];
    int t = threadIdx.x;
    int v = btot[t];
    s[t] = v;
    __syncthreads();
    for (int off = 1; off < 1024; off <<= 1) {
        int x = (t >= off) ? s[t - off] : 0;
        __syncthreads();
        s[t] += x;
        __syncthreads();
    }
    bbase[t] = s[t] - v;   // exclusive
}

// partition: each (block,bucket) writes to its exclusive contiguous range
__global__ __launch_bounds__(256) void bpart(const int* __restrict__ rows, const int* __restrict__ cols,
                                             const float* __restrict__ w, const int* __restrict__ gh,
                                             const int* __restrict__ bbase, uint2* __restrict__ stg)
{
    __shared__ int cur[NBUK];
    int blk = blockIdx.x;
    for (int i = threadIdx.x; i < NBUK; i += 256)
        cur[i] = bbase[i] + gh[i * NCH + blk];
    __syncthreads();
    int base = blk * CHUNK;
    int end  = base + CHUNK; if (end > N_EDGES) end = N_EDGES;
    for (int i = base + threadIdx.x; i < end; i += 256) {
        int r = rows[i];
        int b = r / RPB;
        int pos = atomicAdd(&cur[b], 1);
        float ws = w[i] * ((1.0f - ALPHA) / 16.0f);
        unsigned meta = (unsigned)cols[i] | ((unsigned)(r - b * RPB) << 17);
        stg[pos] = make_uint2(meta, __float_as_uint(ws));
    }
}

// pass 2: one block per bucket; LDS row cursors; bucket window is L2-local.
__global__ __launch_bounds__(256) void bucket_sort(const int* __restrict__ rowp,
                                                   const uint2* __restrict__ stg,
                                                   unsigned long long* __restrict__ cw)
{
    __shared__ int lcur[RPB];
    int b = blockIdx.x;
    int rowlo = b * RPB;
    if (rowlo >= N_NODES) return;
    int rowhi = rowlo + RPB; if (rowhi > N_NODES) rowhi = N_NODES;
    int nrows = rowhi - rowlo;
    for (int r = threadIdx.x; r < nrows; r += 256) lcur[r] = rowp[rowlo + r];
    __syncthreads();
    int base = rowp[rowlo];
    int cnt  = rowp[rowhi] - base;
    for (int j = threadIdx.x; j < cnt; j += 256) {
        uint2 rec = stg[base + j];
        int roff = rec.x >> 17;
        unsigned col = rec.x & 0x1FFFFu;
        int pos = atomicAdd(&lcur[roff], 1);
        cw[pos] = (unsigned long long)col | ((unsigned long long)rec.y << 32);
    }
}

// ---------------------------------------------------------------------------
// SpMM on scaled fp16 state: q_t = sum w' * q_{t-1}[col] + beta_t * z
// ---------------------------------------------------------------------------
template <int LAST>
__global__ __launch_bounds__(256) void spmm_kernel(
    const int* __restrict__ rowp, const unsigned long long* __restrict__ cw,
    const __half* __restrict__ qin, const float* __restrict__ z,
    float beta, float outscale,
    __half* __restrict__ qout, float* __restrict__ out)
{
    const int wid = blockIdx.x * 4 + (threadIdx.x >> 6);
    if (wid >= N_NODES) return;
    const int lane = threadIdx.x & 63;
    const int sub  = lane >> 4;
    const int l16  = lane & 15;

    const int start = rowp[wid];
    const int end   = rowp[wid + 1];

    float ax = 0.f, ay = 0.f, az = 0.f, aw = 0.f;
    int e = start + sub;
    for (; e + 4 < end; e += 8) {
        unsigned long long pc0 = cw[e];
        unsigned long long pc1 = cw[e + 4];
        int   c0  = (int)(unsigned)pc0;
        int   c1  = (int)(unsigned)pc1;
        float w0 = __uint_as_float((unsigned)(pc0 >> 32));
        float w1 = __uint_as_float((unsigned)(pc1 >> 32));
        uint2 v0 = *(const uint2*)(qin + (long)c0 * 64 + l16 * 4);
        uint2 v1 = *(const uint2*)(qin + (long)c1 * 64 + l16 * 4);
        __half2 a0 = *reinterpret_cast<__half2*>(&v0.x);
        __half2 a1 = *reinterpret_cast<__half2*>(&v0.y);
        __half2 b0 = *reinterpret_cast<__half2*>(&v1.x);
        __half2 b1 = *reinterpret_cast<__half2*>(&v1.y);
        float2 f0 = __half22float2(a0), f1 = __half22float2(a1);
        float2 g0 = __half22float2(b0), g1 = __half22float2(b1);
        ax += w0 * f0.x + w1 * g0.x;
        ay += w0 * f0.y + w1 * g0.y;
        az += w0 * f1.x + w1 * g1.x;
        aw += w0 * f1.y + w1 * g1.y;
    }
    if (e < end) {
        unsigned long long pc = cw[e];
        int   c  = (int)(unsigned)pc;
        float ww = __uint_as_float((unsigned)(pc >> 32));
        uint2 v = *(const uint2*)(qin + (long)c * 64 + l16 * 4);
        __half2 h0 = *reinterpret_cast<__half2*>(&v.x);
        __half2 h1 = *reinterpret_cast<__half2*>(&v.y);
        float2 f0 = __half22float2(h0);
        float2 f1 = __half22float2(h1);
        ax += ww * f0.x; ay += ww * f0.y; az += ww * f1.x; aw += ww * f1.y;
    }
    ax += __shfl_xor(ax, 16); ay += __shfl_xor(ay, 16);
    az += __shfl_xor(az, 16); aw += __shfl_xor(aw, 16);
    ax += __shfl_xor(ax, 32); ay += __shfl_xor(ay, 32);
    az += __shfl_xor(az, 32); aw += __shfl_xor(aw, 32);

    if (sub == 0) {
        float4 zv = *(const float4*)(z + (long)wid * 64 + l16 * 4);
        float ox = ax + beta * zv.x;
        float oy = ay + beta * zv.y;
        float oz = az + beta * zv.z;
        float ow = aw + beta * zv.w;
        if (LAST) {
            float4 o = { outscale * ox, outscale * oy, outscale * oz, outscale * ow };
            *(float4*)(out + (long)wid * 64 + l16 * 4) = o;
        } else {
            __half2 p0 = __floats2half2_rn(ox, oy);
            __half2 p1 = __floats2half2_rn(oz, ow);
            uint2 pv = { *(unsigned*)&p0, *(unsigned*)&p1 };
            *(uint2*)(qout + (long)wid * 64 + l16 * 4) = pv;
        }
    }
}

// ---------------------------------------------------------------------------
extern "C" void kernel_launch(void* const* d_in, const int* in_sizes, int n_in,
                              void* d_out, int out_size, void* d_ws, size_t ws_size,
                              hipStream_t stream)
{
    const float* features = (const float*)d_in[0];
    const float* W1 = (const float*)d_in[1];
    const float* b1 = (const float*)d_in[2];
    const float* W2 = (const float*)d_in[3];
    const float* b2 = (const float*)d_in[4];
    const float* ew = (const float*)d_in[5];
    const int*   ei = (const int*)d_in[6];
    const int* erow = ei;
    const int* ecol = ei + N_EDGES;
    float* out = (float*)d_out;

    char* ws = (char*)d_ws;
    size_t off = 0;
    auto alloc = [&](size_t bytes) {
        size_t c = off;
        off += (bytes + 255) & ~(size_t)255;
        return c;
    };
    float* z      = (float*)(ws + alloc((size_t)N_NODES * 64 * 4));
    __half* q0    = (__half*)(ws + alloc((size_t)N_NODES * 64 * 2));
    __half* qA    = (__half*)(ws + alloc((size_t)N_NODES * 64 * 2));
    unsigned long long* cw = (unsigned long long*)(ws + alloc((size_t)N_EDGES * 8));
    uint2* stg    = (uint2*)(ws + alloc((size_t)N_EDGES * 8));
    int*   gh     = (int*)  (ws + alloc((size_t)NBUK * NCH * 4));
    short* W1t    = (short*)(ws + alloc((size_t)512 * 64 * 2));
    short* W2t    = (short*)(ws + alloc((size_t)64 * 64 * 2));
    int*   deg    = (int*)  (ws + alloc((size_t)N_NODES * 4));
    int*   rowp   = (int*)  (ws + alloc((size_t)(N_NODES + 1) * 4));
    int*   btot   = (int*)  (ws + alloc((size_t)NBUK * 4));
    int*   bbase  = (int*)  (ws + alloc((size_t)NBUK * 4));
    int*   bsum   = (int*)  (ws + alloc((size_t)512 * 4));
    int*   boff   = (int*)  (ws + alloc((size_t)512 * 4));
    (void)ws_size; (void)in_sizes; (void)n_in; (void)out_size;

    // 1) weight prep + MLP head (writes z fp32 and q0 fp16)
    prep_w<<<128, 256, 0, stream>>>(W1, W2, W1t, W2t);
    mlp_mfma<<<(N_NODES + 63) / 64, 256, 0, stream>>>(features, W1t, W2t, b1, b2, z, q0);

    // 2a) row-level CSR pointers
    hipMemsetAsync(deg, 0, (size_t)N_NODES * 4, stream);
    hist_kernel<<<(N_EDGES + 255) / 256, 256, 0, stream>>>(erow, deg, N_EDGES);
    const int nb = (N_NODES + 255) / 256;  // 391
    block_sum_kernel<<<nb, 256, 0, stream>>>(deg, bsum, N_NODES);
    scan_bsum_kernel<<<1, 512, 0, stream>>>(bsum, boff, nb);
    scan_chunks_kernel<<<nb, 256, 0, stream>>>(deg, boff, rowp, N_NODES);

    // 2b) radix partition by bucket (no global atomics), then in-bucket row sort
    bhist<<<NCH, 256, 0, stream>>>(erow, gh);
    bscan<<<NBUK, 512, 0, stream>>>(gh, btot);
    scan_btot<<<1, 1024, 0, stream>>>(btot, bbase);
    bpart<<<NCH, 256, 0, stream>>>(erow, ecol, ew, gh, bbase, stg);
    bucket_sort<<<NBUK, 256, 0, stream>>>(rowp, stg, cw);

    // 3) 10 propagation iterations on scaled fp16 state (c = 16)
    const __half* qi = q0;
    for (int it = 1; it < ITERS; ++it) {
        __half* qo = (it & 1) ? qA : q0;
        float beta = (float)(0.1 / pow(16.0, (double)it));
        spmm_kernel<0><<<(N_NODES + 3) / 4, 256, 0, stream>>>(rowp, cw, qi, z, beta, 1.0f, qo, nullptr);
        qi = qo;
    }
    float beta10 = (float)(0.1 / pow(16.0, 10.0));
    float osc    = (float)pow(16.0, 10.0);
    spmm_kernel<1><<<(N_NODES + 3) / 4, 256, 0, stream>>>(rowp, cw, qi, z, beta10, osc, nullptr, out);
}

// Round 6
// 768.956 us; speedup vs baseline: 2.0755x; 1.3699x over previous
//
#include <hip/hip_runtime.h>
#include <hip/hip_fp16.h>
#include <cmath>

#define N_NODES 100000
#define N_EDGES 3200000
#define ALPHA   0.1f
#define ITERS   10
#define NBUK    1024
#define RPB     98      // rows per bucket; NBUK*RPB = 100352 >= N_NODES
#define CHUNK   8192
#define NCH     391     // ceil(N_EDGES / CHUNK)

typedef __attribute__((ext_vector_type(8))) short short8;
typedef __attribute__((ext_vector_type(4))) float f32x4;

__device__ __forceinline__ short f2bf(float x) {
    union { float f; unsigned u; } v; v.f = x;
    unsigned r = v.u + 0x7fffu + ((v.u >> 16) & 1u);   // RNE
    return (short)(r >> 16);
}

// ---------------------------------------------------------------------------
// One-time weight prep: W1[512][64] -> W1t[64][512] bf16 ; W2 -> W2t bf16
// ---------------------------------------------------------------------------
__global__ void prep_w(const float* __restrict__ W1, const float* __restrict__ W2,
                       short* __restrict__ W1t, short* __restrict__ W2t)
{
    int t = blockIdx.x * 256 + threadIdx.x;
    if (t < 512 * 64) { int k = t >> 6, c = t & 63; W1t[c * 512 + k] = f2bf(W1[t]); }
    if (t < 64 * 64)  { int k = t >> 6, c = t & 63; W2t[c * 64 + k]  = f2bf(W2[t]); }
}

// ---------------------------------------------------------------------------
// Fused MFMA MLP with register-prefetch pipelining.
// z = relu(F @ W1 + b1) @ W2 + b2 ; also writes q0 = fp16(z).
// ---------------------------------------------------------------------------
__global__ __launch_bounds__(256) void mlp_mfma(
    const float* __restrict__ F, const short* __restrict__ W1t,
    const short* __restrict__ W2t, const float* __restrict__ b1,
    const float* __restrict__ b2, float* __restrict__ z, __half* __restrict__ q0)
{
    __shared__ short Ft[64 * 128];
    __shared__ short Wt[64 * 128];
    __shared__ short Ht[64 * 64];
    __shared__ short W2s[64 * 64];

    const int t  = threadIdx.x;
    const int l  = t & 63;
    const int wv = t >> 6;
    const int wr = wv * 16;
    const long base = (long)blockIdx.x * 64;

    const int sr = t >> 4;          // staging row group 0..15
    const int sk = (t & 15) * 8;    // staging k offset (8 elems)

    float4 f0a, f0b, f1a, f1b, f2a, f2b, f3a, f3b;
    uint4  w0v, w1v, w2v, w3v;

#define LOAD_TILE(kt) do {                                                   \
    long g0 = base + sr;      if (g0 > N_NODES - 1) g0 = N_NODES - 1;        \
    long g1 = base + sr + 16; if (g1 > N_NODES - 1) g1 = N_NODES - 1;        \
    long g2 = base + sr + 32; if (g2 > N_NODES - 1) g2 = N_NODES - 1;        \
    long g3 = base + sr + 48; if (g3 > N_NODES - 1) g3 = N_NODES - 1;        \
    f0a = *(const float4*)(F + g0 * 512 + (kt) * 128 + sk);                  \
    f0b = *(const float4*)(F + g0 * 512 + (kt) * 128 + sk + 4);              \
    f1a = *(const float4*)(F + g1 * 512 + (kt) * 128 + sk);                  \
    f1b = *(const float4*)(F + g1 * 512 + (kt) * 128 + sk + 4);              \
    f2a = *(const float4*)(F + g2 * 512 + (kt) * 128 + sk);                  \
    f2b = *(const float4*)(F + g2 * 512 + (kt) * 128 + sk + 4);              \
    f3a = *(const float4*)(F + g3 * 512 + (kt) * 128 + sk);                  \
    f3b = *(const float4*)(F + g3 * 512 + (kt) * 128 + sk + 4);              \
    w0v = *(const uint4*)(W1t + (sr     ) * 512 + (kt) * 128 + sk);          \
    w1v = *(const uint4*)(W1t + (sr + 16) * 512 + (kt) * 128 + sk);          \
    w2v = *(const uint4*)(W1t + (sr + 32) * 512 + (kt) * 128 + sk);          \
    w3v = *(const uint4*)(W1t + (sr + 48) * 512 + (kt) * 128 + sk);          \
} while (0)

#define STORE_ROW(row, fa, fb, wreg) do {                                    \
    int r_ = (row);                                                          \
    short8 s_ = { f2bf((fa).x), f2bf((fa).y), f2bf((fa).z), f2bf((fa).w),    \
                  f2bf((fb).x), f2bf((fb).y), f2bf((fb).z), f2bf((fb).w) };  \
    *(short8*)&Ft[(r_ * 128 + sk) ^ ((r_ & 7) << 3)] = s_;                   \
    *(uint4*)&Wt[(r_ * 128 + sk) ^ ((r_ & 7) << 3)] = (wreg);                \
} while (0)

    LOAD_TILE(0);
    uint4 w2pa, w2pb;
    {
        int r2 = t >> 3, k2 = (t & 7) * 8;
        w2pa = *(const uint4*)(W2t + r2 * 64 + k2);
        w2pb = *(const uint4*)(W2t + (r2 + 32) * 64 + k2);
    }

    f32x4 acc[4] = {};
    for (int kt = 0; kt < 4; ++kt) {
        STORE_ROW(sr,      f0a, f0b, w0v);
        STORE_ROW(sr + 16, f1a, f1b, w1v);
        STORE_ROW(sr + 32, f2a, f2b, w2v);
        STORE_ROW(sr + 48, f3a, f3b, w3v);
        if (kt == 0) {
            int r2 = t >> 3, k2 = (t & 7) * 8;
            *(uint4*)&W2s[(r2 * 64 + k2) ^ ((r2 & 7) << 3)] = w2pa;
            *(uint4*)&W2s[((r2 + 32) * 64 + k2) ^ (((r2 + 32) & 7) << 3)] = w2pb;
        }
        __syncthreads();
        if (kt < 3) LOAD_TILE(kt + 1);   // prefetch next tile under MFMA
#pragma unroll
        for (int kc = 0; kc < 4; ++kc) {
            int kb = kc * 32 + (l >> 4) * 8;
            int ar = wr + (l & 15);
            short8 a = *(const short8*)&Ft[(ar * 128 + kb) ^ ((ar & 7) << 3)];
#pragma unroll
            for (int n = 0; n < 4; ++n) {
                int bc = n * 16 + (l & 15);
                short8 b = *(const short8*)&Wt[(bc * 128 + kb) ^ ((bc & 7) << 3)];
                acc[n] = __builtin_amdgcn_mfma_f32_16x16x32_bf16(a, b, acc[n], 0, 0, 0);
            }
        }
        __syncthreads();
    }

#pragma unroll
    for (int n = 0; n < 4; ++n) {
        int col = n * 16 + (l & 15);
        float bv = b1[col];
#pragma unroll
        for (int i = 0; i < 4; ++i) {
            int row = wr + (l >> 4) * 4 + i;
            float hv = fmaxf(acc[n][i] + bv, 0.0f);
            Ht[(row * 64 + col) ^ ((row & 7) << 3)] = f2bf(hv);
        }
    }
    f32x4 acc2[4] = {};
#pragma unroll
    for (int kc = 0; kc < 2; ++kc) {
        int kb = kc * 32 + (l >> 4) * 8;
        int ar = wr + (l & 15);
        short8 a = *(const short8*)&Ht[(ar * 64 + kb) ^ ((ar & 7) << 3)];
#pragma unroll
        for (int n = 0; n < 4; ++n) {
            int bc = n * 16 + (l & 15);
            short8 b = *(const short8*)&W2s[(bc * 64 + kb) ^ ((bc & 7) << 3)];
            acc2[n] = __builtin_amdgcn_mfma_f32_16x16x32_bf16(a, b, acc2[n], 0, 0, 0);
        }
    }
#pragma unroll
    for (int n = 0; n < 4; ++n) {
        int col = n * 16 + (l & 15);
        float bv = b2[col];
#pragma unroll
        for (int i = 0; i < 4; ++i) {
            long row = base + wr + (l >> 4) * 4 + i;
            if (row < N_NODES) {
                float zv = acc2[n][i] + bv;
                z[row * 64 + col]  = zv;
                q0[row * 64 + col] = __float2half(zv);
            }
        }
    }
#undef LOAD_TILE
#undef STORE_ROW
}

// ---------------------------------------------------------------------------
// Radix-partition by bucket (no global atomics):
// bhist -> bscan -> scan_btot -> bpart -> bucket_sort2 (also emits rowp)
// ---------------------------------------------------------------------------
__global__ __launch_bounds__(256) void bhist(const int* __restrict__ rows, int* __restrict__ gh)
{
    __shared__ int cnt[NBUK];
    for (int i = threadIdx.x; i < NBUK; i += 256) cnt[i] = 0;
    __syncthreads();
    int base = blockIdx.x * CHUNK;
    int end  = base + CHUNK; if (end > N_EDGES) end = N_EDGES;
    for (int i = base + threadIdx.x; i < end; i += 256)
        atomicAdd(&cnt[rows[i] / RPB], 1);
    __syncthreads();
    for (int i = threadIdx.x; i < NBUK; i += 256)
        gh[i * NCH + blockIdx.x] = cnt[i];
}

__global__ __launch_bounds__(512) void bscan(int* __restrict__ gh, int* __restrict__ btot)
{
    __shared__ int s[512];
    int k = blockIdx.x;
    int t = threadIdx.x;
    int v = (t < NCH) ? gh[k * NCH + t] : 0;
    s[t] = v;
    __syncthreads();
    for (int off = 1; off < 512; off <<= 1) {
        int x = (t >= off) ? s[t - off] : 0;
        __syncthreads();
        s[t] += x;
        __syncthreads();
    }
    if (t < NCH) gh[k * NCH + t] = s[t] - v;
    if (t == NCH - 1) btot[k] = s[t];
}

__global__ __launch_bounds__(1024) void scan_btot(const int* __restrict__ btot, int* __restrict__ bbase)
{
    __shared__ int s[1024];
    int t = threadIdx.x;
    int v = btot[t];
    s[t] = v;
    __syncthreads();
    for (int off = 1; off < 1024; off <<= 1) {
        int x = (t >= off) ? s[t - off] : 0;
        __syncthreads();
        s[t] += x;
        __syncthreads();
    }
    bbase[t] = s[t] - v;
}

__global__ __launch_bounds__(256) void bpart(const int* __restrict__ rows, const int* __restrict__ cols,
                                             const float* __restrict__ w, const int* __restrict__ gh,
                                             const int* __restrict__ bbase, uint2* __restrict__ stg)
{
    __shared__ int cur[NBUK];
    int blk = blockIdx.x;
    for (int i = threadIdx.x; i < NBUK; i += 256)
        cur[i] = bbase[i] + gh[i * NCH + blk];
    __syncthreads();
    int base = blk * CHUNK;
    int end  = base + CHUNK; if (end > N_EDGES) end = N_EDGES;
    for (int i = base + threadIdx.x; i < end; i += 256) {
        int r = rows[i];
        int b = r / RPB;
        int pos = atomicAdd(&cur[b], 1);
        float ws = w[i] * ((1.0f - ALPHA) / 16.0f);
        unsigned meta = (unsigned)cols[i] | ((unsigned)(r - b * RPB) << 17);
        stg[pos] = make_uint2(meta, __float_as_uint(ws));
    }
}

// one block per bucket: count row degrees (LDS), scan, emit rowp, scatter to cw
__global__ __launch_bounds__(256) void bucket_sort2(const int* __restrict__ bbase,
                                                    const uint2* __restrict__ stg,
                                                    unsigned long long* __restrict__ cw,
                                                    int* __restrict__ rowp)
{
    __shared__ int ldeg[RPB];
    __shared__ int lcur[RPB];
    __shared__ int sc[128];
    const int b = blockIdx.x;
    const int rowlo = b * RPB;
    if (rowlo >= N_NODES) return;
    int rowhi = rowlo + RPB; if (rowhi > N_NODES) rowhi = N_NODES;
    const int nrows = rowhi - rowlo;
    const int t = threadIdx.x;
    const int base = bbase[b];
    const int cnt = ((b + 1 < NBUK) ? bbase[b + 1] : N_EDGES) - base;

    if (t < RPB) ldeg[t] = 0;
    __syncthreads();
    for (int j = t; j < cnt; j += 256)
        atomicAdd(&ldeg[stg[base + j].x >> 17], 1);
    __syncthreads();
    int v = 0;
    if (t < 128) { v = (t < nrows) ? ldeg[t] : 0; sc[t] = v; }
    __syncthreads();
    for (int off = 1; off < 128; off <<= 1) {
        int x = (t < 128 && t >= off) ? sc[t - off] : 0;
        __syncthreads();
        if (t < 128) sc[t] += x;
        __syncthreads();
    }
    if (t < nrows) {
        int rp = base + sc[t] - v;
        rowp[rowlo + t] = rp;
        lcur[t] = rp;
    }
    if (t == 0 && rowhi == N_NODES) rowp[N_NODES] = base + cnt;
    __syncthreads();
    for (int j = t; j < cnt; j += 256) {
        uint2 rec = stg[base + j];
        int roff = rec.x >> 17;
        unsigned col = rec.x & 0x1FFFFu;
        int pos = atomicAdd(&lcur[roff], 1);
        cw[pos] = (unsigned long long)col | ((unsigned long long)rec.y << 32);
    }
}

// ---------------------------------------------------------------------------
// SpMM on scaled fp16 state: q_t = sum w' * q_{t-1}[col] + beta_t * z
// One wave per row; 8 sub-slots x 8 lanes x 16B gathers, 16 edges in flight.
// ---------------------------------------------------------------------------
template <int LAST>
__global__ __launch_bounds__(256) void spmm_kernel(
    const int* __restrict__ rowp, const unsigned long long* __restrict__ cw,
    const __half* __restrict__ qin, const float* __restrict__ z,
    float beta, float outscale,
    __half* __restrict__ qout, float* __restrict__ out)
{
    const int wid = blockIdx.x * 4 + (threadIdx.x >> 6);
    if (wid >= N_NODES) return;
    const int lane = threadIdx.x & 63;
    const int sub  = lane >> 3;   // 0..7
    const int l8   = lane & 7;    // 16B chunk (8 labels)

    const int start = rowp[wid];
    const int end   = rowp[wid + 1];

    float a0 = 0, a1 = 0, a2 = 0, a3 = 0, a4 = 0, a5 = 0, a6 = 0, a7 = 0;
    int e = start + sub;
    for (; e + 8 < end; e += 16) {
        unsigned long long pc0 = cw[e];
        unsigned long long pc1 = cw[e + 8];
        int c0 = (int)(unsigned)pc0;
        int c1 = (int)(unsigned)pc1;
        float w0 = __uint_as_float((unsigned)(pc0 >> 32));
        float w1 = __uint_as_float((unsigned)(pc1 >> 32));
        uint4 v0 = *(const uint4*)(qin + (long)c0 * 64 + l8 * 8);
        uint4 v1 = *(const uint4*)(qin + (long)c1 * 64 + l8 * 8);
        float2 p;
        p = __half22float2(*(__half2*)&v0.x); a0 += w0 * p.x; a1 += w0 * p.y;
        p = __half22float2(*(__half2*)&v0.y); a2 += w0 * p.x; a3 += w0 * p.y;
        p = __half22float2(*(__half2*)&v0.z); a4 += w0 * p.x; a5 += w0 * p.y;
        p = __half22float2(*(__half2*)&v0.w); a6 += w0 * p.x; a7 += w0 * p.y;
        p = __half22float2(*(__half2*)&v1.x); a0 += w1 * p.x; a1 += w1 * p.y;
        p = __half22float2(*(__half2*)&v1.y); a2 += w1 * p.x; a3 += w1 * p.y;
        p = __half22float2(*(__half2*)&v1.z); a4 += w1 * p.x; a5 += w1 * p.y;
        p = __half22float2(*(__half2*)&v1.w); a6 += w1 * p.x; a7 += w1 * p.y;
    }
    if (e < end) {
        unsigned long long pc = cw[e];
        int c = (int)(unsigned)pc;
        float ww = __uint_as_float((unsigned)(pc >> 32));
        uint4 v0 = *(const uint4*)(qin + (long)c * 64 + l8 * 8);
        float2 p;
        p = __half22float2(*(__half2*)&v0.x); a0 += ww * p.x; a1 += ww * p.y;
        p = __half22float2(*(__half2*)&v0.y); a2 += ww * p.x; a3 += ww * p.y;
        p = __half22float2(*(__half2*)&v0.z); a4 += ww * p.x; a5 += ww * p.y;
        p = __half22float2(*(__half2*)&v0.w); a6 += ww * p.x; a7 += ww * p.y;
    }
    a0 += __shfl_xor(a0, 8);  a1 += __shfl_xor(a1, 8);
    a2 += __shfl_xor(a2, 8);  a3 += __shfl_xor(a3, 8);
    a4 += __shfl_xor(a4, 8);  a5 += __shfl_xor(a5, 8);
    a6 += __shfl_xor(a6, 8);  a7 += __shfl_xor(a7, 8);
    a0 += __shfl_xor(a0, 16); a1 += __shfl_xor(a1, 16);
    a2 += __shfl_xor(a2, 16); a3 += __shfl_xor(a3, 16);
    a4 += __shfl_xor(a4, 16); a5 += __shfl_xor(a5, 16);
    a6 += __shfl_xor(a6, 16); a7 += __shfl_xor(a7, 16);
    a0 += __shfl_xor(a0, 32); a1 += __shfl_xor(a1, 32);
    a2 += __shfl_xor(a2, 32); a3 += __shfl_xor(a3, 32);
    a4 += __shfl_xor(a4, 32); a5 += __shfl_xor(a5, 32);
    a6 += __shfl_xor(a6, 32); a7 += __shfl_xor(a7, 32);

    if (lane < 8) {
        float4 za = *(const float4*)(z + (long)wid * 64 + lane * 8);
        float4 zb = *(const float4*)(z + (long)wid * 64 + lane * 8 + 4);
        float o0 = a0 + beta * za.x, o1 = a1 + beta * za.y;
        float o2 = a2 + beta * za.z, o3 = a3 + beta * za.w;
        float o4 = a4 + beta * zb.x, o5 = a5 + beta * zb.y;
        float o6 = a6 + beta * zb.z, o7 = a7 + beta * zb.w;
        if (LAST) {
            float4 ra = { outscale * o0, outscale * o1, outscale * o2, outscale * o3 };
            float4 rb = { outscale * o4, outscale * o5, outscale * o6, outscale * o7 };
            *(float4*)(out + (long)wid * 64 + lane * 8)     = ra;
            *(float4*)(out + (long)wid * 64 + lane * 8 + 4) = rb;
        } else {
            __half2 h0 = __floats2half2_rn(o0, o1);
            __half2 h1 = __floats2half2_rn(o2, o3);
            __half2 h2 = __floats2half2_rn(o4, o5);
            __half2 h3 = __floats2half2_rn(o6, o7);
            uint4 pv = { *(unsigned*)&h0, *(unsigned*)&h1, *(unsigned*)&h2, *(unsigned*)&h3 };
            *(uint4*)(qout + (long)wid * 64 + lane * 8) = pv;
        }
    }
}

// ---------------------------------------------------------------------------
extern "C" void kernel_launch(void* const* d_in, const int* in_sizes, int n_in,
                              void* d_out, int out_size, void* d_ws, size_t ws_size,
                              hipStream_t stream)
{
    const float* features = (const float*)d_in[0];
    const float* W1 = (const float*)d_in[1];
    const float* b1 = (const float*)d_in[2];
    const float* W2 = (const float*)d_in[3];
    const float* b2 = (const float*)d_in[4];
    const float* ew = (const float*)d_in[5];
    const int*   ei = (const int*)d_in[6];
    const int* erow = ei;
    const int* ecol = ei + N_EDGES;
    float* out = (float*)d_out;

    char* ws = (char*)d_ws;
    size_t off = 0;
    auto alloc = [&](size_t bytes) {
        size_t c = off;
        off += (bytes + 255) & ~(size_t)255;
        return c;
    };
    float* z      = (float*)(ws + alloc((size_t)N_NODES * 64 * 4));
    __half* q0    = (__half*)(ws + alloc((size_t)N_NODES * 64 * 2));
    __half* qA    = (__half*)(ws + alloc((size_t)N_NODES * 64 * 2));
    unsigned long long* cw = (unsigned long long*)(ws + alloc((size_t)N_EDGES * 8));
    uint2* stg    = (uint2*)(ws + alloc((size_t)N_EDGES * 8));
    int*   gh     = (int*)  (ws + alloc((size_t)NBUK * NCH * 4));
    short* W1t    = (short*)(ws + alloc((size_t)512 * 64 * 2));
    short* W2t    = (short*)(ws + alloc((size_t)64 * 64 * 2));
    int*   rowp   = (int*)  (ws + alloc((size_t)(N_NODES + 1) * 4));
    int*   btot   = (int*)  (ws + alloc((size_t)NBUK * 4));
    int*   bbase  = (int*)  (ws + alloc((size_t)NBUK * 4));
    (void)ws_size; (void)in_sizes; (void)n_in; (void)out_size;

    // 1) weight prep + MLP head (writes z fp32 and q0 fp16)
    prep_w<<<128, 256, 0, stream>>>(W1, W2, W1t, W2t);
    mlp_mfma<<<(N_NODES + 63) / 64, 256, 0, stream>>>(features, W1t, W2t, b1, b2, z, q0);

    // 2) CSR build: radix partition by bucket, then in-bucket row sort (+rowp)
    bhist<<<NCH, 256, 0, stream>>>(erow, gh);
    bscan<<<NBUK, 512, 0, stream>>>(gh, btot);
    scan_btot<<<1, 1024, 0, stream>>>(btot, bbase);
    bpart<<<NCH, 256, 0, stream>>>(erow, ecol, ew, gh, bbase, stg);
    bucket_sort2<<<NBUK, 256, 0, stream>>>(bbase, stg, cw, rowp);

    // 3) 10 propagation iterations on scaled fp16 state (c = 16)
    const __half* qi = q0;
    for (int it = 1; it < ITERS; ++it) {
        __half* qo = (it & 1) ? qA : q0;
        float beta = (float)(0.1 / pow(16.0, (double)it));
        spmm_kernel<0><<<(N_NODES + 3) / 4, 256, 0, stream>>>(rowp, cw, qi, z, beta, 1.0f, qo, nullptr);
        qi = qo;
    }
    float beta10 = (float)(0.1 / pow(16.0, 10.0));
    float osc    = (float)pow(16.0, 10.0);
    spmm_kernel<1><<<(N_NODES + 3) / 4, 256, 0, stream>>>(rowp, cw, qi, z, beta10, osc, nullptr, out);
}